// Round 1
// baseline (111.503 us; speedup 1.0000x reference)
//
#include <hip/hip_runtime.h>

#define NQ 12
#define NL 4
#define DIM 4096              // 2^NQ
#define BLOCK 256
#define PER_T (DIM / BLOCK)   // 16 amplitudes per thread
#define BATCH 256

// One block per batch sample. State lives in LDS as float2 (re, im).
// Qubit q sits at bit position (NQ-1-q) of the flat amplitude index.
__global__ __launch_bounds__(BLOCK) void qcp_kernel(
    const float* __restrict__ x,      // (BATCH, NQ)
    const float* __restrict__ w,      // (NL, NQ, 2) flat: [ry, rz]
    float* __restrict__ out)          // (BATCH,)
{
    __shared__ float2 psi[DIM];
    __shared__ float rbuf[BLOCK / 64];

    const int b = blockIdx.x;
    const int t = threadIdx.x;

    // Load this sample's data row (uniform-ish; 12 scalar loads per thread).
    float xr[NQ];
#pragma unroll
    for (int q = 0; q < NQ; ++q) xr[q] = x[b * NQ + q];
    float xsum = 0.0f;
#pragma unroll
    for (int q = 0; q < NQ; ++q) xsum += xr[q];

    // H^{\otimes 12} |0> = uniform amplitude 2^{-6}
    const float amp0 = 0.015625f;
#pragma unroll
    for (int k = 0; k < PER_T; ++k)
        psi[t + BLOCK * k] = make_float2(amp0, 0.0f);
    __syncthreads();

    for (int l = 0; l < NL; ++l) {
        // ---- 1) fused diagonal data-encoding phase -------------------------
        // factor = exp(i * ang), ang = 0.5 * sum_q (bit_q ? +x_q : -x_q)
#pragma unroll
        for (int k = 0; k < PER_T; ++k) {
            int i = t + BLOCK * k;
            float ang = -0.5f * xsum;   // = 0.5*(-sum); add x_q for set bits
#pragma unroll
            for (int q = 0; q < NQ; ++q)
                if ((i >> (NQ - 1 - q)) & 1) ang += xr[q];
            float sn, cs;
            sincosf(ang, &sn, &cs);
            float2 a = psi[i];
            psi[i] = make_float2(a.x * cs - a.y * sn, a.x * sn + a.y * cs);
        }
        __syncthreads();

        // ---- 2) fused RY(a) then RZ(b) per qubit ---------------------------
        // a0' = e^{-ib/2} (c a0 - s a1);  a1' = e^{+ib/2} (s a0 + c a1)
#pragma unroll
        for (int q = 0; q < NQ; ++q) {
            const int p = NQ - 1 - q;          // bit position of qubit q
            float ry = w[(l * NQ + q) * 2 + 0];
            float rz = w[(l * NQ + q) * 2 + 1];
            float s, c, pi_, pr;
            sincosf(0.5f * ry, &s, &c);
            sincosf(0.5f * rz, &pi_, &pr);
#pragma unroll
            for (int j = 0; j < PER_T / 2; ++j) {
                int m  = t + BLOCK * j;                     // pair index 0..2047
                int lo = m & ((1 << p) - 1);
                int i0 = ((m >> p) << (p + 1)) | lo;
                int i1 = i0 | (1 << p);
                float2 a0 = psi[i0];
                float2 a1 = psi[i1];
                float n0r = c * a0.x - s * a1.x;
                float n0i = c * a0.y - s * a1.y;
                float n1r = s * a0.x + c * a1.x;
                float n1i = s * a0.y + c * a1.y;
                // multiply by (pr, -pi) and (pr, +pi)
                psi[i0] = make_float2(pr * n0r + pi_ * n0i, pr * n0i - pi_ * n0r);
                psi[i1] = make_float2(pr * n1r - pi_ * n1i, pr * n1i + pi_ * n1r);
            }
            __syncthreads();
        }

        // ---- 3) CX ladder as a permutation ---------------------------------
        // new index j gets old amplitude at i = j ^ (j >> 1)
        float2 regv[PER_T];
#pragma unroll
        for (int k = 0; k < PER_T; ++k) {
            int j = t + BLOCK * k;
            regv[k] = psi[j ^ (j >> 1)];
        }
        __syncthreads();
#pragma unroll
        for (int k = 0; k < PER_T; ++k)
            psi[t + BLOCK * k] = regv[k];
        __syncthreads();
    }

    // ---- <Z(0)>: qubit 0 is bit 11 ----------------------------------------
    float acc = 0.0f;
#pragma unroll
    for (int k = 0; k < PER_T; ++k) {
        int i = t + BLOCK * k;
        float2 a = psi[i];
        float p2 = a.x * a.x + a.y * a.y;
        acc += (i & (1 << (NQ - 1))) ? -p2 : p2;
    }
    // wave (64-lane) reduction
#pragma unroll
    for (int off = 32; off > 0; off >>= 1)
        acc += __shfl_down(acc, off, 64);
    if ((t & 63) == 0) rbuf[t >> 6] = acc;
    __syncthreads();
    if (t == 0) {
        float tot = 0.0f;
#pragma unroll
        for (int wv = 0; wv < BLOCK / 64; ++wv) tot += rbuf[wv];
        out[b] = tot;
    }
}

extern "C" void kernel_launch(void* const* d_in, const int* in_sizes, int n_in,
                              void* d_out, int out_size, void* d_ws, size_t ws_size,
                              hipStream_t stream) {
    const float* x = (const float*)d_in[0];   // (256, 12)
    const float* w = (const float*)d_in[1];   // (96,)
    float* out = (float*)d_out;               // (256, 1)
    qcp_kernel<<<BATCH, BLOCK, 0, stream>>>(x, w, out);
}

// Round 2
// 88.089 us; speedup vs baseline: 1.2658x; 1.2658x over previous
//
#include <hip/hip_runtime.h>

#define NQ 12
#define NL 4
#define DIM 4096
#define BLOCK 256
#define PER_T 16          // amplitudes per thread, bits 6..9 of index
#define BATCH 256

// Index layout: j = lane | (k<<6) | (wave<<10)
//   bits 0..5  = lane  -> qubits 6..11 (shuffle gates)
//   bits 6..9  = reg k -> qubits 2..5  (register gates)
//   bits 10..11= wave  -> qubits 0..1  (fused LDS pass with CX permutation)
// Qubit q lives at bit position 11-q.

__device__ __forceinline__ float2 cmul(float2 a, float2 b) {
    return make_float2(a.x * b.x - a.y * b.y, a.x * b.y + a.y * b.x);
}

__global__ __launch_bounds__(BLOCK) void qcp_kernel(
    const float* __restrict__ x,      // (BATCH, NQ)
    const float* __restrict__ w,      // (NL, NQ, 2): [ry, rz]
    float* __restrict__ out)          // (BATCH,)
{
    __shared__ float2 sbuf[DIM];
    __shared__ float rbuf[4];

    const int b    = blockIdx.x;
    const int t    = threadIdx.x;
    const int lane = t & 63;
    const int wv   = t >> 6;

    float xr[NQ];
#pragma unroll
    for (int q = 0; q < NQ; ++q) xr[q] = x[b * NQ + q];

    // Data-encoding phasors: identical every layer -> precompute per reg.
    // ang(j) = sum_q (bit_{11-q}(j) ? +x_q/2 : -x_q/2)
    float2 eph[PER_T];
#pragma unroll
    for (int k = 0; k < PER_T; ++k) {
        int j = lane | (k << 6) | (wv << 10);
        float ang = 0.0f;
#pragma unroll
        for (int q = 0; q < NQ; ++q)
            ang += ((j >> (NQ - 1 - q)) & 1) ? 0.5f * xr[q] : -0.5f * xr[q];
        sincosf(ang, &eph[k].y, &eph[k].x);
    }

    // |psi> = H^{x12}|0>
    float2 psi[PER_T];
#pragma unroll
    for (int k = 0; k < PER_T; ++k) psi[k] = make_float2(0.015625f, 0.0f);

    for (int l = 0; l < NL; ++l) {
        // ---- 1) diagonal data-encoding phase (register-local) --------------
#pragma unroll
        for (int k = 0; k < PER_T; ++k) psi[k] = cmul(psi[k], eph[k]);

        // ---- 2) register-bit gates: qubits 2..5 (k bit 5-q) ----------------
#pragma unroll
        for (int q = 2; q <= 5; ++q) {
            const int kb = 5 - q;
            float s, c, zi, zr;
            sincosf(0.5f * w[(l * NQ + q) * 2 + 0], &s, &c);
            sincosf(0.5f * w[(l * NQ + q) * 2 + 1], &zi, &zr);
#pragma unroll
            for (int m = 0; m < PER_T / 2; ++m) {
                int k0 = ((m >> kb) << (kb + 1)) | (m & ((1 << kb) - 1));
                int k1 = k0 | (1 << kb);
                float2 a0 = psi[k0], a1 = psi[k1];
                float n0r = c * a0.x - s * a1.x;
                float n0i = c * a0.y - s * a1.y;
                float n1r = s * a0.x + c * a1.x;
                float n1i = s * a0.y + c * a1.y;
                psi[k0] = make_float2(n0r * zr + n0i * zi, n0i * zr - n0r * zi);
                psi[k1] = make_float2(n1r * zr - n1i * zi, n1i * zr + n1r * zi);
            }
        }

        // ---- 3) lane-bit gates: qubits 6..11 (shuffle, no barriers) --------
#pragma unroll
        for (int q = 6; q <= 11; ++q) {
            const int p = NQ - 1 - q;          // lane bit
            const int msk = 1 << p;
            float s, c, zi, zr;
            sincosf(0.5f * w[(l * NQ + q) * 2 + 0], &s, &c);
            sincosf(0.5f * w[(l * NQ + q) * 2 + 1], &zi, &zr);
            const int sb = (lane >> p) & 1;
            const float se  = sb ? s  : -s;    // coefficient on partner
            const float zie = sb ? zi : -zi;   // RZ phase sign
#pragma unroll
            for (int k = 0; k < PER_T; ++k) {
                float px = __shfl_xor(psi[k].x, msk, 64);
                float py = __shfl_xor(psi[k].y, msk, 64);
                float nr = c * psi[k].x + se * px;
                float ni = c * psi[k].y + se * py;
                psi[k].x = nr * zr - ni * zie;
                psi[k].y = ni * zr + nr * zie;
            }
        }

        // ---- 4) fused: qubits 0..1 gates (bits 11,10) + CX-ladder perm -----
        // out[j] = sum_{c'} U4[row(g(j))][c'] * psi_staged[(g(j)&0x3FF)|(c'<<10)]
        // with g(j) = j ^ (j>>1); row bits are wave-uniform.
#pragma unroll
        for (int k = 0; k < PER_T; ++k) {
            int j = lane | (k << 6) | (wv << 10);
            sbuf[j] = psi[k];
        }

        float sA, cA, ziA, zrA, sB, cB, ziB, zrB;
        sincosf(0.5f * w[(l * NQ + 0) * 2 + 0], &sA, &cA);
        sincosf(0.5f * w[(l * NQ + 0) * 2 + 1], &ziA, &zrA);
        sincosf(0.5f * w[(l * NQ + 1) * 2 + 0], &sB, &cB);
        sincosf(0.5f * w[(l * NQ + 1) * 2 + 1], &ziB, &zrB);
        const int rb1 = wv >> 1;               // bit11 of g(j)
        const int rb0 = (wv & 1) ^ rb1;        // bit10 of g(j)
        // G_q[row][col] = RY entry (real) * RZ phase(row)
        float  e00 = rb1 ? sA : cA,  e01 = rb1 ? cA : -sA;
        float2 phA = make_float2(zrA, rb1 ? ziA : -ziA);
        float2 g0c0 = make_float2(e00 * phA.x, e00 * phA.y);
        float2 g0c1 = make_float2(e01 * phA.x, e01 * phA.y);
        float  f00 = rb0 ? sB : cB,  f01 = rb0 ? cB : -sB;
        float2 phB = make_float2(zrB, rb0 ? ziB : -ziB);
        float2 g1c0 = make_float2(f00 * phB.x, f00 * phB.y);
        float2 g1c1 = make_float2(f01 * phB.x, f01 * phB.y);
        float2 coef0 = cmul(g0c0, g1c0);   // c' = 0 (bit11=0,bit10=0)
        float2 coef1 = cmul(g0c0, g1c1);   // c' = 1 (bit10=1)
        float2 coef2 = cmul(g0c1, g1c0);   // c' = 2 (bit11=1)
        float2 coef3 = cmul(g0c1, g1c1);   // c' = 3

        __syncthreads();
#pragma unroll
        for (int k = 0; k < PER_T; ++k) {
            int j = lane | (k << 6) | (wv << 10);
            int g = j ^ (j >> 1);
            int base = g & 0x3FF;
            float2 v0 = sbuf[base];
            float2 v1 = sbuf[base | 0x400];
            float2 v2 = sbuf[base | 0x800];
            float2 v3 = sbuf[base | 0xC00];
            float2 r;
            r.x = coef0.x * v0.x - coef0.y * v0.y
                + coef1.x * v1.x - coef1.y * v1.y
                + coef2.x * v2.x - coef2.y * v2.y
                + coef3.x * v3.x - coef3.y * v3.y;
            r.y = coef0.x * v0.y + coef0.y * v0.x
                + coef1.x * v1.y + coef1.y * v1.x
                + coef2.x * v2.y + coef2.y * v2.x
                + coef3.x * v3.y + coef3.y * v3.x;
            psi[k] = r;
        }
        __syncthreads();
    }

    // ---- <Z(0)>: qubit 0 = bit 11 = wave bit 1 (uniform per thread) --------
    float acc = 0.0f;
#pragma unroll
    for (int k = 0; k < PER_T; ++k)
        acc += psi[k].x * psi[k].x + psi[k].y * psi[k].y;
    if (wv >= 2) acc = -acc;
#pragma unroll
    for (int off = 32; off > 0; off >>= 1)
        acc += __shfl_down(acc, off, 64);
    if (lane == 0) rbuf[wv] = acc;
    __syncthreads();
    if (t == 0) out[b] = rbuf[0] + rbuf[1] + rbuf[2] + rbuf[3];
}

extern "C" void kernel_launch(void* const* d_in, const int* in_sizes, int n_in,
                              void* d_out, int out_size, void* d_ws, size_t ws_size,
                              hipStream_t stream) {
    const float* x = (const float*)d_in[0];   // (256, 12)
    const float* w = (const float*)d_in[1];   // (96,)
    float* out = (float*)d_out;               // (256, 1)
    qcp_kernel<<<BATCH, BLOCK, 0, stream>>>(x, w, out);
}

// Round 3
// 83.731 us; speedup vs baseline: 1.3317x; 1.0520x over previous
//
#include <hip/hip_runtime.h>

#define NQ 12
#define NL 4
#define DIM 4096
#define BLOCK 1024
#define PER_T 4           // amplitudes per thread, bits 6..7 of index
#define BATCH 256

// Index layout: j = lane | (k<<6) | (wv<<8)
//   bits 0..5  = lane (64)  -> qubits 6..11 (shuffle gates)
//   bits 6..7  = reg k (4)  -> qubits 4..5  (register gates)
//   bits 8..11 = wave (16)  -> qubits 0..3  (fused LDS pass with CX perm)
// Qubit q lives at bit position 11-q.

__device__ __forceinline__ float2 cmul(float2 a, float2 b) {
    return make_float2(a.x * b.x - a.y * b.y, a.x * b.y + a.y * b.x);
}

__global__ __launch_bounds__(BLOCK, 4) void qcp_kernel(
    const float* __restrict__ x,      // (BATCH, NQ)
    const float* __restrict__ w,      // (NL, NQ, 2) flat: [ry, rz] -> 96
    float* __restrict__ out)          // (BATCH,)
{
    __shared__ float2 sbuf[DIM];
    __shared__ float2 trig[NL * NQ * 2];   // (cos, sin) of 0.5*w[idx]
    __shared__ float rbuf[16];

    const int b    = blockIdx.x;
    const int t    = threadIdx.x;
    const int lane = t & 63;
    const int wv   = t >> 6;               // 0..15

    // ---- shared-weight trig, computed once per block (96 sincosf total) ----
    if (t < NL * NQ * 2) {
        float sn, cs;
        sincosf(0.5f * w[t], &sn, &cs);
        trig[t] = make_float2(cs, sn);
    }

    float xr[NQ];
#pragma unroll
    for (int q = 0; q < NQ; ++q) xr[q] = x[b * NQ + q];

    // Data-encoding phasors (same every layer): 4 sincosf per thread.
    float2 eph[PER_T];
#pragma unroll
    for (int k = 0; k < PER_T; ++k) {
        int j = lane | (k << 6) | (wv << 8);
        float ang = 0.0f;
#pragma unroll
        for (int q = 0; q < NQ; ++q)
            ang += ((j >> (NQ - 1 - q)) & 1) ? 0.5f * xr[q] : -0.5f * xr[q];
        sincosf(ang, &eph[k].y, &eph[k].x);
    }

    float2 psi[PER_T];
#pragma unroll
    for (int k = 0; k < PER_T; ++k) psi[k] = make_float2(0.015625f, 0.0f);

    __syncthreads();   // trig ready

    for (int l = 0; l < NL; ++l) {
        // ---- 1) diagonal data-encoding phase -------------------------------
#pragma unroll
        for (int k = 0; k < PER_T; ++k) psi[k] = cmul(psi[k], eph[k]);

        // ---- 2) register-bit gates: qubits 4..5 (k bit 5-q) ----------------
#pragma unroll
        for (int q = 4; q <= 5; ++q) {
            const int kb = 5 - q;
            float2 tr = trig[(l * NQ + q) * 2 + 0];
            float2 tz = trig[(l * NQ + q) * 2 + 1];
            float c = tr.x, s = tr.y, zr = tz.x, zi = tz.y;
#pragma unroll
            for (int m = 0; m < PER_T / 2; ++m) {
                int k0 = ((m >> kb) << (kb + 1)) | (m & ((1 << kb) - 1));
                int k1 = k0 | (1 << kb);
                float2 a0 = psi[k0], a1 = psi[k1];
                float n0r = c * a0.x - s * a1.x;
                float n0i = c * a0.y - s * a1.y;
                float n1r = s * a0.x + c * a1.x;
                float n1i = s * a0.y + c * a1.y;
                psi[k0] = make_float2(n0r * zr + n0i * zi, n0i * zr - n0r * zi);
                psi[k1] = make_float2(n1r * zr - n1i * zi, n1i * zr + n1r * zi);
            }
        }

        // ---- 3) lane-bit gates: qubits 6..11 (shuffles, no barriers) -------
#pragma unroll
        for (int q = 6; q <= 11; ++q) {
            const int p = NQ - 1 - q;
            const int msk = 1 << p;
            float2 tr = trig[(l * NQ + q) * 2 + 0];
            float2 tz = trig[(l * NQ + q) * 2 + 1];
            float c = tr.x, s = tr.y, zr = tz.x, zi = tz.y;
            const int sb = (lane >> p) & 1;
            const float se  = sb ? s  : -s;
            const float zie = sb ? zi : -zi;
#pragma unroll
            for (int k = 0; k < PER_T; ++k) {
                float px = __shfl_xor(psi[k].x, msk, 64);
                float py = __shfl_xor(psi[k].y, msk, 64);
                float nr = c * psi[k].x + se * px;
                float ni = c * psi[k].y + se * py;
                psi[k].x = nr * zr - ni * zie;
                psi[k].y = ni * zr + nr * zie;
            }
        }

        // ---- 4) fused: qubits 0..3 gates (bits 11..8) + CX-ladder perm -----
        // psi_new[j] = sum_c coef[c] * staged[(g(j)&0xFF) | (c<<8)], g=j^(j>>1)
#pragma unroll
        for (int k = 0; k < PER_T; ++k) {
            int j = lane | (k << 6) | (wv << 8);
            sbuf[j] = psi[k];
        }

        // row bits of g(j) on bits 11..8 are wave-uniform
        const int r0 = (wv >> 3) & 1;
        const int r1 = ((wv >> 2) ^ (wv >> 3)) & 1;
        const int r2 = ((wv >> 1) ^ (wv >> 2)) & 1;
        const int r3 = (wv ^ (wv >> 1)) & 1;
        const int rr[4] = {r0, r1, r2, r3};
        float2 E[4][2];
#pragma unroll
        for (int q = 0; q < 4; ++q) {
            float2 tr = trig[(l * NQ + q) * 2 + 0];
            float2 tz = trig[(l * NQ + q) * 2 + 1];
            float cq = tr.x, sq = tr.y;
            int r = rr[q];
            float e0 = r ? sq : cq;       // col 0
            float e1 = r ? cq : -sq;      // col 1
            float2 ph = make_float2(tz.x, r ? tz.y : -tz.y);
            E[q][0] = make_float2(e0 * ph.x, e0 * ph.y);
            E[q][1] = make_float2(e1 * ph.x, e1 * ph.y);
        }
        float2 pAB[4], pCD[4], coef[16];
#pragma unroll
        for (int a = 0; a < 2; ++a)
#pragma unroll
            for (int c2 = 0; c2 < 2; ++c2) {
                pAB[(a << 1) | c2] = cmul(E[0][a], E[1][c2]);
                pCD[(a << 1) | c2] = cmul(E[2][a], E[3][c2]);
            }
#pragma unroll
        for (int c2 = 0; c2 < 16; ++c2)
            coef[c2] = cmul(pAB[c2 >> 2], pCD[c2 & 3]);

        __syncthreads();
#pragma unroll
        for (int k = 0; k < PER_T; ++k) {
            int j = lane | (k << 6) | (wv << 8);
            int g = j ^ (j >> 1);
            int base = g & 0xFF;
            float2 r = make_float2(0.0f, 0.0f);
#pragma unroll
            for (int c2 = 0; c2 < 16; ++c2) {
                float2 v = sbuf[base | (c2 << 8)];
                r.x += coef[c2].x * v.x - coef[c2].y * v.y;
                r.y += coef[c2].x * v.y + coef[c2].y * v.x;
            }
            psi[k] = r;
        }
        __syncthreads();
    }

    // ---- <Z(0)>: qubit 0 = bit 11 = wave bit 3 ----------------------------
    float acc = 0.0f;
#pragma unroll
    for (int k = 0; k < PER_T; ++k)
        acc += psi[k].x * psi[k].x + psi[k].y * psi[k].y;
    if (wv >= 8) acc = -acc;
#pragma unroll
    for (int off = 32; off > 0; off >>= 1)
        acc += __shfl_down(acc, off, 64);
    if (lane == 0) rbuf[wv] = acc;
    __syncthreads();
    if (t == 0) {
        float tot = 0.0f;
#pragma unroll
        for (int i = 0; i < 16; ++i) tot += rbuf[i];
        out[b] = tot;
    }
}

extern "C" void kernel_launch(void* const* d_in, const int* in_sizes, int n_in,
                              void* d_out, int out_size, void* d_ws, size_t ws_size,
                              hipStream_t stream) {
    const float* x = (const float*)d_in[0];   // (256, 12)
    const float* w = (const float*)d_in[1];   // (96,)
    float* out = (float*)d_out;               // (256, 1)
    qcp_kernel<<<BATCH, BLOCK, 0, stream>>>(x, w, out);
}

// Round 4
// 74.937 us; speedup vs baseline: 1.4880x; 1.1174x over previous
//
#include <hip/hip_runtime.h>

#define NQ 12
#define NL 4
#define DIM 4096
#define BLOCK 1024
#define PER_T 4           // amplitudes per thread, bits 6..7 of index
#define BATCH 256

// Index layout: j = lane | (k<<6) | (wv<<8)
//   bits 0..5  = lane (64)  -> qubits 6..11 (shuffle/DPP gates)
//   bits 6..7  = reg k (4)  -> qubits 4..5  (register gates)
//   bits 8..11 = wave (16)  -> qubits 0..3  (two 4-point LDS stages + CX perm)
// Qubit q lives at bit position 11-q.

__device__ __forceinline__ float2 cmul(float2 a, float2 b) {
    return make_float2(a.x * b.x - a.y * b.y, a.x * b.y + a.y * b.x);
}

// VALU-pipe lane exchange via DPP (no DS traffic).
// xor1: quad_perm[1,0,3,2]=0xB1; xor2: quad_perm[2,3,0,1]=0x4E; xor8: row_ror:8=0x128.
template <int CTRL>
__device__ __forceinline__ float dppx(float v) {
    int i = __builtin_bit_cast(int, v);
    int r = __builtin_amdgcn_update_dpp(0, i, CTRL, 0xF, 0xF, true);
    return __builtin_bit_cast(float, r);
}

template <int MSK, int CTRL>
__device__ __forceinline__ void gate_dpp(float2* psi, int lane,
                                         float c, float s, float zr, float zi) {
    const float se  = (lane & MSK) ? s  : -s;
    const float zie = (lane & MSK) ? zi : -zi;
#pragma unroll
    for (int k = 0; k < PER_T; ++k) {
        float px = dppx<CTRL>(psi[k].x);
        float py = dppx<CTRL>(psi[k].y);
        float nr = c * psi[k].x + se * px;
        float ni = c * psi[k].y + se * py;
        psi[k].x = nr * zr - ni * zie;
        psi[k].y = ni * zr + nr * zie;
    }
}

template <int MSK>
__device__ __forceinline__ void gate_shfl(float2* psi, int lane,
                                          float c, float s, float zr, float zi) {
    const float se  = (lane & MSK) ? s  : -s;
    const float zie = (lane & MSK) ? zi : -zi;
#pragma unroll
    for (int k = 0; k < PER_T; ++k) {
        float px = __shfl_xor(psi[k].x, MSK, 64);
        float py = __shfl_xor(psi[k].y, MSK, 64);
        float nr = c * psi[k].x + se * px;
        float ni = c * psi[k].y + se * py;
        psi[k].x = nr * zr - ni * zie;
        psi[k].y = ni * zr + nr * zie;
    }
}

__global__ __launch_bounds__(BLOCK, 4) void qcp_kernel(
    const float* __restrict__ x,      // (BATCH, NQ)
    const float* __restrict__ w,      // (NL, NQ, 2) flat: [ry, rz] -> 96
    float* __restrict__ out)          // (BATCH,)
{
    __shared__ float2 sA[DIM];
    __shared__ float2 sB[DIM];
    __shared__ float2 trig[NL * NQ * 2];   // (cos, sin) of 0.5*w[idx]
    __shared__ float rbuf[16];

    const int b    = blockIdx.x;
    const int t    = threadIdx.x;
    const int lane = t & 63;
    const int wv   = t >> 6;               // 0..15

    if (t < NL * NQ * 2) {
        float sn, cs;
        sincosf(0.5f * w[t], &sn, &cs);
        trig[t] = make_float2(cs, sn);
    }

    float xr[NQ];
#pragma unroll
    for (int q = 0; q < NQ; ++q) xr[q] = x[b * NQ + q];

    // Data-encoding phasors (identical each layer).
    float2 eph[PER_T];
#pragma unroll
    for (int k = 0; k < PER_T; ++k) {
        int j = lane | (k << 6) | (wv << 8);
        float ang = 0.0f;
#pragma unroll
        for (int q = 0; q < NQ; ++q)
            ang += ((j >> (NQ - 1 - q)) & 1) ? 0.5f * xr[q] : -0.5f * xr[q];
        sincosf(ang, &eph[k].y, &eph[k].x);
    }

    float2 psi[PER_T];
#pragma unroll
    for (int k = 0; k < PER_T; ++k) psi[k] = make_float2(0.015625f, 0.0f);

    __syncthreads();   // trig ready

    for (int l = 0; l < NL; ++l) {
        // ---- 1) diagonal data-encoding phase -------------------------------
#pragma unroll
        for (int k = 0; k < PER_T; ++k) psi[k] = cmul(psi[k], eph[k]);

        // ---- 2) register-bit gates: qubits 4..5 ----------------------------
#pragma unroll
        for (int q = 4; q <= 5; ++q) {
            const int kb = 5 - q;
            float2 tr = trig[(l * NQ + q) * 2 + 0];
            float2 tz = trig[(l * NQ + q) * 2 + 1];
            float c = tr.x, s = tr.y, zr = tz.x, zi = tz.y;
#pragma unroll
            for (int m = 0; m < PER_T / 2; ++m) {
                int k0 = ((m >> kb) << (kb + 1)) | (m & ((1 << kb) - 1));
                int k1 = k0 | (1 << kb);
                float2 a0 = psi[k0], a1 = psi[k1];
                float n0r = c * a0.x - s * a1.x;
                float n0i = c * a0.y - s * a1.y;
                float n1r = s * a0.x + c * a1.x;
                float n1i = s * a0.y + c * a1.y;
                psi[k0] = make_float2(n0r * zr + n0i * zi, n0i * zr - n0r * zi);
                psi[k1] = make_float2(n1r * zr - n1i * zi, n1i * zr + n1r * zi);
            }
        }

        // ---- 3) lane-bit gates: qubits 6..11 -------------------------------
        {
            const float2* tg = &trig[l * NQ * 2];
            // q=6: mask 32 (shfl), q=7: mask 16 (shfl), q=8: mask 8 (DPP),
            // q=9: mask 4 (shfl), q=10: mask 2 (DPP), q=11: mask 1 (DPP)
            gate_shfl<32>(psi, lane, tg[12].x, tg[12].y, tg[13].x, tg[13].y);
            gate_shfl<16>(psi, lane, tg[14].x, tg[14].y, tg[15].x, tg[15].y);
            gate_dpp<8, 0x128>(psi, lane, tg[16].x, tg[16].y, tg[17].x, tg[17].y);
            gate_shfl<4>(psi, lane, tg[18].x, tg[18].y, tg[19].x, tg[19].y);
            gate_dpp<2, 0x4E>(psi, lane, tg[20].x, tg[20].y, tg[21].x, tg[21].y);
            gate_dpp<1, 0xB1>(psi, lane, tg[22].x, tg[22].y, tg[23].x, tg[23].y);
        }

        // ---- 4) wave-bit gates (qubits 0..3) + CX perm, two 4-point stages -
        // E[q][col], row-dependent entries: col0 = r? s: c, col1 = r? c: -s,
        // times RZ phase (zr, r? zi : -zi).
        float2 E0[2], E1[2], E2[2], E3[2];
        {
            const int r0 = (wv >> 3) & 1;                 // g bit11
            const int r1 = ((wv >> 2) ^ (wv >> 3)) & 1;   // g bit10
            const int r2 = (wv >> 1) & 1;                 // j bit9
            const int r3 = wv & 1;                        // j bit8
            const int rr[4] = {r0, r1, r2, r3};
            float2* EE[4] = {E0, E1, E2, E3};
#pragma unroll
            for (int q = 0; q < 4; ++q) {
                float2 tr = trig[(l * NQ + q) * 2 + 0];
                float2 tz = trig[(l * NQ + q) * 2 + 1];
                int r = rr[q];
                float e0 = r ? tr.y : tr.x;
                float e1 = r ? tr.x : -tr.y;
                float2 ph = make_float2(tz.x, r ? tz.y : -tz.y);
                EE[q][0] = make_float2(e0 * ph.x, e0 * ph.y);
                EE[q][1] = make_float2(e1 * ph.x, e1 * ph.y);
            }
        }
        float2 cA[4], cB[4];
#pragma unroll
        for (int c2 = 0; c2 < 4; ++c2) {
            cA[c2] = cmul(E2[c2 >> 1], E3[c2 & 1]);   // addr bits (9,8) = c2
            cB[c2] = cmul(E0[c2 >> 1], E1[c2 & 1]);   // addr bits (11,10) = c2
        }

        // stage the shuffled state
#pragma unroll
        for (int k = 0; k < PER_T; ++k) {
            int j = lane | (k << 6) | (wv << 8);
            sA[j] = psi[k];
        }
        __syncthreads();

        // stage A: t[j] = sum_c (G2 x G3) picks over bits 9,8
#pragma unroll
        for (int k = 0; k < PER_T; ++k) {
            int base = lane | (k << 6) | ((wv >> 2) << 10);
            float2 r = make_float2(0.0f, 0.0f);
#pragma unroll
            for (int c = 0; c < 4; ++c) {
                float2 v = sA[base | (c << 8)];
                r.x += cA[c].x * v.x - cA[c].y * v.y;
                r.y += cA[c].x * v.y + cA[c].y * v.x;
            }
            sB[lane | (k << 6) | (wv << 8)] = r;
        }
        __syncthreads();

        // stage B: psi[j] = sum_c (G0 x G1) over bits 11,10 at perm'd base
#pragma unroll
        for (int k = 0; k < PER_T; ++k) {
            int j = lane | (k << 6) | (wv << 8);
            int g = j ^ (j >> 1);
            int base = g & 0x3FF;
            float2 r = make_float2(0.0f, 0.0f);
#pragma unroll
            for (int c = 0; c < 4; ++c) {
                float2 v = sB[base | (c << 10)];
                r.x += cB[c].x * v.x - cB[c].y * v.y;
                r.y += cB[c].x * v.y + cB[c].y * v.x;
            }
            psi[k] = r;
        }
        __syncthreads();
    }

    // ---- <Z(0)>: qubit 0 = bit 11 = wave bit 3 ----------------------------
    float acc = 0.0f;
#pragma unroll
    for (int k = 0; k < PER_T; ++k)
        acc += psi[k].x * psi[k].x + psi[k].y * psi[k].y;
    if (wv >= 8) acc = -acc;
#pragma unroll
    for (int off = 32; off > 0; off >>= 1)
        acc += __shfl_down(acc, off, 64);
    if (lane == 0) rbuf[wv] = acc;
    __syncthreads();
    if (t == 0) {
        float tot = 0.0f;
#pragma unroll
        for (int i = 0; i < 16; ++i) tot += rbuf[i];
        out[b] = tot;
    }
}

extern "C" void kernel_launch(void* const* d_in, const int* in_sizes, int n_in,
                              void* d_out, int out_size, void* d_ws, size_t ws_size,
                              hipStream_t stream) {
    const float* x = (const float*)d_in[0];   // (256, 12)
    const float* w = (const float*)d_in[1];   // (96,)
    float* out = (float*)d_out;               // (256, 1)
    qcp_kernel<<<BATCH, BLOCK, 0, stream>>>(x, w, out);
}